// Round 1
// baseline (92.639 us; speedup 1.0000x reference)
//
#include <hip/hip_runtime.h>
#include <hip/hip_bf16.h>

#define T_DIM 2048
#define B_DIM 2
#define E_DIM 256
#define H_DIM 8
#define D_DIM 32
#define M_DIM (T_DIM*B_DIM)   // 4096

typedef __bf16 bf16x8 __attribute__((ext_vector_type(8)));
typedef __bf16 bf16x4 __attribute__((ext_vector_type(4)));
typedef float  f32x4  __attribute__((ext_vector_type(4)));

// ---------------- Kernel 0: f32 -> bf16 convert ----------------
__global__ void cvt_kernel(const float* __restrict__ src, __bf16* __restrict__ dst, int n) {
    int i = (blockIdx.x * blockDim.x + threadIdx.x) * 4;
    if (i < n) {
        float4 v = *(const float4*)(src + i);
        bf16x4 o;
        o[0] = (__bf16)v.x; o[1] = (__bf16)v.y; o[2] = (__bf16)v.z; o[3] = (__bf16)v.w;
        *(bf16x4*)(dst + i) = o;
    }
}

// ---------------- Kernel 1: fused QKV projection ----------------
// grid (64, 12): blockIdx.x = m-tile (64 rows), blockIdx.y: 0-3 q, 4-7 k, 8-11 v
__global__ __launch_bounds__(256)
void qkv_kernel(const __bf16* __restrict__ X,
                const __bf16* __restrict__ Wq, const __bf16* __restrict__ Wk, const __bf16* __restrict__ Wv,
                const float* __restrict__ bq, const float* __restrict__ bk, const float* __restrict__ bv,
                __bf16* __restrict__ qh, __bf16* __restrict__ kh, __bf16* __restrict__ vT) {
    __shared__ __align__(16) __bf16 Xs[64][136];
    __shared__ __align__(16) __bf16 Ws[64][136];
    const int m0 = blockIdx.x * 64;
    const int which = blockIdx.y >> 2;        // 0 q, 1 k, 2 v
    const int n0 = (blockIdx.y & 3) * 64;
    const __bf16* W = (which == 0) ? Wq : (which == 1) ? Wk : Wv;
    const float* bias = (which == 0) ? bq : (which == 1) ? bk : bv;
    const int tid = threadIdx.x;
    const int wid = tid >> 6, lane = tid & 63;
    const int wm = (wid & 1) * 32, wn = (wid >> 1) * 32;
    const int lr = lane & 15, lg = lane >> 4;

    f32x4 acc[2][2] = {};
    for (int kc = 0; kc < 2; ++kc) {
        for (int c = tid; c < 1024; c += 256) {
            int row = c >> 4, col = (c & 15) * 8;
            *(bf16x8*)&Xs[row][col] = *(const bf16x8*)&X[(size_t)(m0 + row) * E_DIM + kc * 128 + col];
            *(bf16x8*)&Ws[row][col] = *(const bf16x8*)&W[(size_t)(n0 + row) * E_DIM + kc * 128 + col];
        }
        __syncthreads();
#pragma unroll
        for (int ks = 0; ks < 4; ++ks) {
            bf16x8 a0 = *(const bf16x8*)&Xs[wm + lr][ks * 32 + lg * 8];
            bf16x8 a1 = *(const bf16x8*)&Xs[wm + 16 + lr][ks * 32 + lg * 8];
            bf16x8 b0 = *(const bf16x8*)&Ws[wn + lr][ks * 32 + lg * 8];
            bf16x8 b1 = *(const bf16x8*)&Ws[wn + 16 + lr][ks * 32 + lg * 8];
            acc[0][0] = __builtin_amdgcn_mfma_f32_16x16x32_bf16(a0, b0, acc[0][0], 0, 0, 0);
            acc[0][1] = __builtin_amdgcn_mfma_f32_16x16x32_bf16(a0, b1, acc[0][1], 0, 0, 0);
            acc[1][0] = __builtin_amdgcn_mfma_f32_16x16x32_bf16(a1, b0, acc[1][0], 0, 0, 0);
            acc[1][1] = __builtin_amdgcn_mfma_f32_16x16x32_bf16(a1, b1, acc[1][1], 0, 0, 0);
        }
        __syncthreads();
    }
    const float scale = 0.17677669529663687f;  // 1/sqrt(32)
#pragma unroll
    for (int mt = 0; mt < 2; ++mt) {
#pragma unroll
        for (int nt = 0; nt < 2; ++nt) {
            int n = n0 + wn + nt * 16 + lr;            // 0..255
            float bb = bias[n];
            int h = n >> 5, d = n & 31;
#pragma unroll
            for (int r = 0; r < 4; ++r) {
                int m = m0 + wm + mt * 16 + lg * 4 + r;
                int t = m >> 1, b = m & 1;
                float v = acc[mt][nt][r] + bb;
                if (which == 0) {
                    v *= scale;
                    qh[((size_t)(b * H_DIM + h) * T_DIM + t) * D_DIM + d] = (__bf16)v;
                } else if (which == 1) {
                    kh[((size_t)(b * H_DIM + h) * T_DIM + t) * D_DIM + d] = (__bf16)v;
                } else {
                    vT[((size_t)(b * H_DIM + h) * D_DIM + d) * T_DIM + t] = (__bf16)v;
                }
            }
        }
    }
}

// ---------------- Kernel 2: flash attention ----------------
// grid (T/64, B*H), block 256 (4 waves). Wave w owns q-rows [t0 + 16w, t0 + 16w + 15].
__global__ __launch_bounds__(256)
void attn_kernel(const __bf16* __restrict__ qh, const __bf16* __restrict__ kh,
                 const __bf16* __restrict__ vT, const float* __restrict__ attn_bias,
                 __bf16* __restrict__ attn) {
    __shared__ __align__(16) __bf16 Ks[64][40];    // K tile [s][d], pad to 40
    __shared__ __align__(16) __bf16 VTs[32][72];   // V^T tile [d][s], pad to 72
    __shared__ __align__(16) __bf16 Ps[4][16][72]; // per-wave P tile [t][s]
    const int t0 = blockIdx.x * 64;
    const int bh = blockIdx.y;
    const int b = bh >> 3, h = bh & 7;
    const int tid = threadIdx.x, wid = tid >> 6, lane = tid & 63;
    const int lr = lane & 15, lg = lane >> 4;

    // Q fragment: A[m=t][k=d], m = lane&15, k-chunk = (lane>>4)*8
    bf16x8 qf = *(const bf16x8*)&qh[((size_t)bh * T_DIM + t0 + wid * 16 + lr) * D_DIM + lg * 8];

    float m_r[4] = {-1e30f, -1e30f, -1e30f, -1e30f};
    float l_r[4] = {0.f, 0.f, 0.f, 0.f};
    f32x4 o[2] = {};

    const float* brow = attn_bias + (size_t)b * T_DIM * T_DIM;
    const int tg = t0 + wid * 16 + lg * 4;

    for (int st = 0; st < T_DIM / 64; ++st) {
        const int s0 = st * 64;
        __syncthreads();
        { // stage K: 64 rows x 32 cols
            int row = tid >> 2, col = (tid & 3) * 8;
            *(bf16x8*)&Ks[row][col] = *(const bf16x8*)&kh[((size_t)bh * T_DIM + s0 + row) * D_DIM + col];
        }
        { // stage V^T: 32 rows x 64 cols
            int row = tid >> 3, col = (tid & 7) * 8;
            *(bf16x8*)&VTs[row][col] = *(const bf16x8*)&vT[((size_t)bh * D_DIM + row) * T_DIM + s0 + col];
        }
        __syncthreads();

        // S = Q K^T + bias (bias enters via MFMA C operand)
        f32x4 s[4];
#pragma unroll
        for (int nt = 0; nt < 4; ++nt) {
            int sg = s0 + nt * 16 + lr;
            f32x4 c;
#pragma unroll
            for (int r = 0; r < 4; ++r) c[r] = brow[(size_t)(tg + r) * T_DIM + sg];
            bf16x8 kf = *(const bf16x8*)&Ks[nt * 16 + lr][lg * 8];
            s[nt] = __builtin_amdgcn_mfma_f32_16x16x32_bf16(qf, kf, c, 0, 0, 0);
        }

        // online softmax, per register-row r (row t = tg + r, cols across 16 lanes of group)
#pragma unroll
        for (int r = 0; r < 4; ++r) {
            float mx = fmaxf(fmaxf(s[0][r], s[1][r]), fmaxf(s[2][r], s[3][r]));
            mx = fmaxf(mx, __shfl_xor(mx, 1));
            mx = fmaxf(mx, __shfl_xor(mx, 2));
            mx = fmaxf(mx, __shfl_xor(mx, 4));
            mx = fmaxf(mx, __shfl_xor(mx, 8));
            float mnew = fmaxf(m_r[r], mx);
            float sc = __expf(m_r[r] - mnew);
            m_r[r] = mnew;
            float sum = 0.f;
#pragma unroll
            for (int nt = 0; nt < 4; ++nt) {
                float p = __expf(s[nt][r] - mnew);
                s[nt][r] = p;
                sum += p;
            }
            sum += __shfl_xor(sum, 1);
            sum += __shfl_xor(sum, 2);
            sum += __shfl_xor(sum, 4);
            sum += __shfl_xor(sum, 8);
            l_r[r] = l_r[r] * sc + sum;
            o[0][r] *= sc;
            o[1][r] *= sc;
        }

        // P -> LDS (bf16), per-wave region, then PV
#pragma unroll
        for (int nt = 0; nt < 4; ++nt)
#pragma unroll
            for (int r = 0; r < 4; ++r)
                Ps[wid][lg * 4 + r][nt * 16 + lr] = (__bf16)s[nt][r];

#pragma unroll
        for (int kt = 0; kt < 2; ++kt) {
            bf16x8 pf = *(const bf16x8*)&Ps[wid][lr][kt * 32 + lg * 8];
#pragma unroll
            for (int dt = 0; dt < 2; ++dt) {
                bf16x8 vf = *(const bf16x8*)&VTs[dt * 16 + lr][kt * 32 + lg * 8];
                o[dt] = __builtin_amdgcn_mfma_f32_16x16x32_bf16(pf, vf, o[dt], 0, 0, 0);
            }
        }
    }

    // epilogue: normalize and write attn [t*B+b][h*32+d] as bf16
#pragma unroll
    for (int r = 0; r < 4; ++r) {
        float inv = 1.0f / l_r[r];
        int t = t0 + wid * 16 + lg * 4 + r;
#pragma unroll
        for (int dt = 0; dt < 2; ++dt) {
            int col = h * D_DIM + dt * 16 + lr;
            attn[((size_t)t * B_DIM + b) * E_DIM + col] = (__bf16)(o[dt][r] * inv);
        }
    }
}

// ---------------- Kernel 3: output projection ----------------
// grid (64, 4): out[m][n] = sum_k attn[m][k] * Wo[n][k] + bo[n], f32 out
__global__ __launch_bounds__(256)
void oproj_kernel(const __bf16* __restrict__ X, const __bf16* __restrict__ Wo,
                  const float* __restrict__ bo, float* __restrict__ out) {
    __shared__ __align__(16) __bf16 Xs[64][136];
    __shared__ __align__(16) __bf16 Ws[64][136];
    const int m0 = blockIdx.x * 64;
    const int n0 = blockIdx.y * 64;
    const int tid = threadIdx.x;
    const int wid = tid >> 6, lane = tid & 63;
    const int wm = (wid & 1) * 32, wn = (wid >> 1) * 32;
    const int lr = lane & 15, lg = lane >> 4;

    f32x4 acc[2][2] = {};
    for (int kc = 0; kc < 2; ++kc) {
        for (int c = tid; c < 1024; c += 256) {
            int row = c >> 4, col = (c & 15) * 8;
            *(bf16x8*)&Xs[row][col] = *(const bf16x8*)&X[(size_t)(m0 + row) * E_DIM + kc * 128 + col];
            *(bf16x8*)&Ws[row][col] = *(const bf16x8*)&Wo[(size_t)(n0 + row) * E_DIM + kc * 128 + col];
        }
        __syncthreads();
#pragma unroll
        for (int ks = 0; ks < 4; ++ks) {
            bf16x8 a0 = *(const bf16x8*)&Xs[wm + lr][ks * 32 + lg * 8];
            bf16x8 a1 = *(const bf16x8*)&Xs[wm + 16 + lr][ks * 32 + lg * 8];
            bf16x8 b0 = *(const bf16x8*)&Ws[wn + lr][ks * 32 + lg * 8];
            bf16x8 b1 = *(const bf16x8*)&Ws[wn + 16 + lr][ks * 32 + lg * 8];
            acc[0][0] = __builtin_amdgcn_mfma_f32_16x16x32_bf16(a0, b0, acc[0][0], 0, 0, 0);
            acc[0][1] = __builtin_amdgcn_mfma_f32_16x16x32_bf16(a0, b1, acc[0][1], 0, 0, 0);
            acc[1][0] = __builtin_amdgcn_mfma_f32_16x16x32_bf16(a1, b0, acc[1][0], 0, 0, 0);
            acc[1][1] = __builtin_amdgcn_mfma_f32_16x16x32_bf16(a1, b1, acc[1][1], 0, 0, 0);
        }
        __syncthreads();
    }
#pragma unroll
    for (int mt = 0; mt < 2; ++mt) {
#pragma unroll
        for (int nt = 0; nt < 2; ++nt) {
            int n = n0 + wn + nt * 16 + lr;
            float bb = bo[n];
#pragma unroll
            for (int r = 0; r < 4; ++r) {
                int m = m0 + wm + mt * 16 + lg * 4 + r;
                out[(size_t)m * E_DIM + n] = acc[mt][nt][r] + bb;
            }
        }
    }
}

extern "C" void kernel_launch(void* const* d_in, const int* in_sizes, int n_in,
                              void* d_out, int out_size, void* d_ws, size_t ws_size,
                              hipStream_t stream) {
    const float* query     = (const float*)d_in[0];
    const float* attn_bias = (const float*)d_in[1];
    const float* Wq = (const float*)d_in[2];
    const float* bq = (const float*)d_in[3];
    const float* Wk = (const float*)d_in[4];
    const float* bk = (const float*)d_in[5];
    const float* Wv = (const float*)d_in[6];
    const float* bv = (const float*)d_in[7];
    const float* Wo = (const float*)d_in[8];
    const float* bo = (const float*)d_in[9];
    float* out = (float*)d_out;

    char* ws = (char*)d_ws;
    __bf16* Xbf  = (__bf16*)(ws);                         // 4096*256  = 2 MB
    __bf16* Wqb  = (__bf16*)(ws + 2097152);               // 128 KB
    __bf16* Wkb  = (__bf16*)(ws + 2097152 + 131072);
    __bf16* Wvb  = (__bf16*)(ws + 2097152 + 262144);
    __bf16* Wob  = (__bf16*)(ws + 2097152 + 393216);
    __bf16* qhp  = (__bf16*)(ws + 2621440);               // [B][H][T][D] 2 MB
    __bf16* khp  = (__bf16*)(ws + 4718592);               // [B][H][T][D] 2 MB
    __bf16* vTp  = (__bf16*)(ws + 6815744);               // [B][H][D][T] 2 MB
    __bf16* attn = (__bf16*)(ws + 8912896);               // [M][E] 2 MB

    // convert inputs to bf16
    cvt_kernel<<<dim3(M_DIM * E_DIM / 1024), 256, 0, stream>>>(query, Xbf, M_DIM * E_DIM);
    cvt_kernel<<<dim3(E_DIM * E_DIM / 1024), 256, 0, stream>>>(Wq, Wqb, E_DIM * E_DIM);
    cvt_kernel<<<dim3(E_DIM * E_DIM / 1024), 256, 0, stream>>>(Wk, Wkb, E_DIM * E_DIM);
    cvt_kernel<<<dim3(E_DIM * E_DIM / 1024), 256, 0, stream>>>(Wv, Wvb, E_DIM * E_DIM);
    cvt_kernel<<<dim3(E_DIM * E_DIM / 1024), 256, 0, stream>>>(Wo, Wob, E_DIM * E_DIM);

    // QKV projection
    qkv_kernel<<<dim3(M_DIM / 64, 12), 256, 0, stream>>>(Xbf, Wqb, Wkb, Wvb, bq, bk, bv, qhp, khp, vTp);

    // attention
    attn_kernel<<<dim3(T_DIM / 64, B_DIM * H_DIM), 256, 0, stream>>>(qhp, khp, vTp, attn_bias, attn);

    // output projection
    oproj_kernel<<<dim3(M_DIM / 64, E_DIM / 64), 256, 0, stream>>>(attn, Wob, bo, out);
}

// Round 2
// 78.981 us; speedup vs baseline: 1.1729x; 1.1729x over previous
//
#include <hip/hip_runtime.h>
#include <hip/hip_bf16.h>

#define T_DIM 2048
#define B_DIM 2
#define E_DIM 256
#define H_DIM 8
#define D_DIM 32
#define M_DIM (T_DIM*B_DIM)   // 4096
#define SPLIT 4
#define S_CHUNK (T_DIM/SPLIT) // 512

typedef __bf16 bf16x8 __attribute__((ext_vector_type(8)));
typedef __bf16 bf16x4 __attribute__((ext_vector_type(4)));
typedef float  f32x4  __attribute__((ext_vector_type(4)));

// ---------------- Kernel 0: fused f32 -> bf16 convert ----------------
// Converts query (1048576 elems) + Wq/Wk/Wv/Wo (65536 each, contiguous dst).
__global__ __launch_bounds__(256)
void cvt_all_kernel(const float* __restrict__ query,
                    const float* __restrict__ Wq, const float* __restrict__ Wk,
                    const float* __restrict__ Wv, const float* __restrict__ Wo,
                    __bf16* __restrict__ Xbf, __bf16* __restrict__ Wdst) {
    int idx = (blockIdx.x * 256 + threadIdx.x) * 4;   // elem index, 4 per thread
    const int NX = M_DIM * E_DIM;                     // 1048576
    float4 v;
    __bf16* dst;
    if (idx < NX) {
        v = *(const float4*)(query + idx);
        dst = Xbf + idx;
    } else {
        int j = idx - NX;                             // 0 .. 262143
        int which = j >> 16;                          // 0..3
        int off = j & 65535;
        const float* src = (which == 0) ? Wq : (which == 1) ? Wk : (which == 2) ? Wv : Wo;
        v = *(const float4*)(src + off);
        dst = Wdst + j;
    }
    bf16x4 o;
    o[0] = (__bf16)v.x; o[1] = (__bf16)v.y; o[2] = (__bf16)v.z; o[3] = (__bf16)v.w;
    *(bf16x4*)dst = o;
}

// ---------------- Kernel 1: fused QKV projection ----------------
// grid (64, 12): blockIdx.x = m-tile (64 rows), blockIdx.y: 0-3 q, 4-7 k, 8-11 v
__global__ __launch_bounds__(256)
void qkv_kernel(const __bf16* __restrict__ X, const __bf16* __restrict__ Wall,
                const float* __restrict__ bq, const float* __restrict__ bk, const float* __restrict__ bv,
                __bf16* __restrict__ qh, __bf16* __restrict__ kh, __bf16* __restrict__ vT) {
    __shared__ __align__(16) __bf16 Xs[64][136];
    __shared__ __align__(16) __bf16 Ws[64][136];
    const int m0 = blockIdx.x * 64;
    const int which = blockIdx.y >> 2;        // 0 q, 1 k, 2 v
    const int n0 = (blockIdx.y & 3) * 64;
    const __bf16* W = Wall + (size_t)which * E_DIM * E_DIM;
    const float* bias = (which == 0) ? bq : (which == 1) ? bk : bv;
    const int tid = threadIdx.x;
    const int wid = tid >> 6, lane = tid & 63;
    const int wm = (wid & 1) * 32, wn = (wid >> 1) * 32;
    const int lr = lane & 15, lg = lane >> 4;

    f32x4 acc[2][2] = {};
    for (int kc = 0; kc < 2; ++kc) {
        for (int c = tid; c < 1024; c += 256) {
            int row = c >> 4, col = (c & 15) * 8;
            *(bf16x8*)&Xs[row][col] = *(const bf16x8*)&X[(size_t)(m0 + row) * E_DIM + kc * 128 + col];
            *(bf16x8*)&Ws[row][col] = *(const bf16x8*)&W[(size_t)(n0 + row) * E_DIM + kc * 128 + col];
        }
        __syncthreads();
#pragma unroll
        for (int ks = 0; ks < 4; ++ks) {
            bf16x8 a0 = *(const bf16x8*)&Xs[wm + lr][ks * 32 + lg * 8];
            bf16x8 a1 = *(const bf16x8*)&Xs[wm + 16 + lr][ks * 32 + lg * 8];
            bf16x8 b0 = *(const bf16x8*)&Ws[wn + lr][ks * 32 + lg * 8];
            bf16x8 b1 = *(const bf16x8*)&Ws[wn + 16 + lr][ks * 32 + lg * 8];
            acc[0][0] = __builtin_amdgcn_mfma_f32_16x16x32_bf16(a0, b0, acc[0][0], 0, 0, 0);
            acc[0][1] = __builtin_amdgcn_mfma_f32_16x16x32_bf16(a0, b1, acc[0][1], 0, 0, 0);
            acc[1][0] = __builtin_amdgcn_mfma_f32_16x16x32_bf16(a1, b0, acc[1][0], 0, 0, 0);
            acc[1][1] = __builtin_amdgcn_mfma_f32_16x16x32_bf16(a1, b1, acc[1][1], 0, 0, 0);
        }
        __syncthreads();
    }
    const float scale = 0.17677669529663687f;  // 1/sqrt(32)
#pragma unroll
    for (int mt = 0; mt < 2; ++mt) {
#pragma unroll
        for (int nt = 0; nt < 2; ++nt) {
            int n = n0 + wn + nt * 16 + lr;            // 0..255
            float bb = bias[n];
            int h = n >> 5, d = n & 31;
#pragma unroll
            for (int r = 0; r < 4; ++r) {
                int m = m0 + wm + mt * 16 + lg * 4 + r;
                int t = m >> 1, b = m & 1;
                float v = acc[mt][nt][r] + bb;
                if (which == 0) {
                    v *= scale;
                    qh[((size_t)(b * H_DIM + h) * T_DIM + t) * D_DIM + d] = (__bf16)v;
                } else if (which == 1) {
                    kh[((size_t)(b * H_DIM + h) * T_DIM + t) * D_DIM + d] = (__bf16)v;
                } else {
                    vT[((size_t)(b * H_DIM + h) * D_DIM + d) * T_DIM + t] = (__bf16)v;
                }
            }
        }
    }
}

// ---------------- Kernel 2: flash attention, split over S ----------------
// grid (T/64, B*H, SPLIT), block 256 (4 waves). Wave w owns q-rows [t0+16w, t0+16w+15].
// Each block handles s in [z*512, z*512+512). Partial (unnorm O, m, l) -> workspace.
__global__ __launch_bounds__(256)
void attn_kernel(const __bf16* __restrict__ qh, const __bf16* __restrict__ kh,
                 const __bf16* __restrict__ vT, const float* __restrict__ attn_bias,
                 float* __restrict__ po, float* __restrict__ pml) {
    __shared__ __align__(16) __bf16 Ks[64][40];    // K tile [s][d], pad to 40
    __shared__ __align__(16) __bf16 VTs[32][72];   // V^T tile [d][s], pad to 72
    __shared__ __align__(16) __bf16 Ps[4][16][72]; // per-wave P tile [t][s]
    const int t0 = blockIdx.x * 64;
    const int bh = blockIdx.y;
    const int sp = blockIdx.z;
    const int sbase = sp * S_CHUNK;
    const int b = bh >> 3;
    const int tid = threadIdx.x, wid = tid >> 6, lane = tid & 63;
    const int lr = lane & 15, lg = lane >> 4;

    // Q fragment: A[m=t][k=d], m = lane&15, k-chunk = (lane>>4)*8
    bf16x8 qf = *(const bf16x8*)&qh[((size_t)bh * T_DIM + t0 + wid * 16 + lr) * D_DIM + lg * 8];

    float m_r[4] = {-1e30f, -1e30f, -1e30f, -1e30f};
    float l_r[4] = {0.f, 0.f, 0.f, 0.f};
    f32x4 o[2] = {};

    const float* brow = attn_bias + (size_t)b * T_DIM * T_DIM;
    const int tg = t0 + wid * 16 + lg * 4;

    for (int st = 0; st < S_CHUNK / 64; ++st) {
        const int s0 = sbase + st * 64;

        // hoist bias loads: issue before staging so they overlap LDS traffic
        float cbuf[4][4];
#pragma unroll
        for (int nt = 0; nt < 4; ++nt) {
            int sg = s0 + nt * 16 + lr;
#pragma unroll
            for (int r = 0; r < 4; ++r)
                cbuf[nt][r] = brow[(size_t)(tg + r) * T_DIM + sg];
        }

        __syncthreads();
        { // stage K: 64 rows x 32 cols
            int row = tid >> 2, col = (tid & 3) * 8;
            *(bf16x8*)&Ks[row][col] = *(const bf16x8*)&kh[((size_t)bh * T_DIM + s0 + row) * D_DIM + col];
        }
        { // stage V^T: 32 rows x 64 cols
            int row = tid >> 3, col = (tid & 7) * 8;
            *(bf16x8*)&VTs[row][col] = *(const bf16x8*)&vT[((size_t)bh * D_DIM + row) * T_DIM + s0 + col];
        }
        __syncthreads();

        // S = Q K^T + bias (bias enters via MFMA C operand)
        f32x4 s[4];
#pragma unroll
        for (int nt = 0; nt < 4; ++nt) {
            f32x4 c;
#pragma unroll
            for (int r = 0; r < 4; ++r) c[r] = cbuf[nt][r];
            bf16x8 kf = *(const bf16x8*)&Ks[nt * 16 + lr][lg * 8];
            s[nt] = __builtin_amdgcn_mfma_f32_16x16x32_bf16(qf, kf, c, 0, 0, 0);
        }

        // online softmax per register-row r
#pragma unroll
        for (int r = 0; r < 4; ++r) {
            float mx = fmaxf(fmaxf(s[0][r], s[1][r]), fmaxf(s[2][r], s[3][r]));
            mx = fmaxf(mx, __shfl_xor(mx, 1));
            mx = fmaxf(mx, __shfl_xor(mx, 2));
            mx = fmaxf(mx, __shfl_xor(mx, 4));
            mx = fmaxf(mx, __shfl_xor(mx, 8));
            float mnew = fmaxf(m_r[r], mx);
            float sc = __expf(m_r[r] - mnew);
            m_r[r] = mnew;
            float sum = 0.f;
#pragma unroll
            for (int nt = 0; nt < 4; ++nt) {
                float p = __expf(s[nt][r] - mnew);
                s[nt][r] = p;
                sum += p;
            }
            sum += __shfl_xor(sum, 1);
            sum += __shfl_xor(sum, 2);
            sum += __shfl_xor(sum, 4);
            sum += __shfl_xor(sum, 8);
            l_r[r] = l_r[r] * sc + sum;
            o[0][r] *= sc;
            o[1][r] *= sc;
        }

        // P -> LDS (bf16), per-wave region, then PV
#pragma unroll
        for (int nt = 0; nt < 4; ++nt)
#pragma unroll
            for (int r = 0; r < 4; ++r)
                Ps[wid][lg * 4 + r][nt * 16 + lr] = (__bf16)s[nt][r];

#pragma unroll
        for (int kt = 0; kt < 2; ++kt) {
            bf16x8 pf = *(const bf16x8*)&Ps[wid][lr][kt * 32 + lg * 8];
#pragma unroll
            for (int dt = 0; dt < 2; ++dt) {
                bf16x8 vf = *(const bf16x8*)&VTs[dt * 16 + lr][kt * 32 + lg * 8];
                o[dt] = __builtin_amdgcn_mfma_f32_16x16x32_bf16(pf, vf, o[dt], 0, 0, 0);
            }
        }
    }

    // epilogue: store unnormalized partials
#pragma unroll
    for (int r = 0; r < 4; ++r) {
        int t = t0 + wid * 16 + lg * 4 + r;
        size_t row = (size_t)bh * T_DIM + t;
#pragma unroll
        for (int dt = 0; dt < 2; ++dt)
            po[(row * SPLIT + sp) * D_DIM + dt * 16 + lr] = o[dt][r];
        if (lr == 0) {
            pml[(row * SPLIT + sp) * 2 + 0] = m_r[r];
            pml[(row * SPLIT + sp) * 2 + 1] = l_r[r];
        }
    }
}

// ---------------- Kernel 2b: combine split-S partials ----------------
// thread handles (row, 4 dims). rows = BH*T = 32768, 8 threads/row.
__global__ __launch_bounds__(256)
void combine_kernel(const float* __restrict__ po, const float* __restrict__ pml,
                    __bf16* __restrict__ attn) {
    int idx = blockIdx.x * 256 + threadIdx.x;
    int row = idx >> 3, dg = idx & 7;
    int bh = row >> 11, t = row & 2047;
    int b = bh >> 3, h = bh & 7;

    float mv[SPLIT], lv[SPLIT];
    float M = -1e30f;
#pragma unroll
    for (int sp2 = 0; sp2 < SPLIT; ++sp2) {
        mv[sp2] = pml[((size_t)row * SPLIT + sp2) * 2 + 0];
        lv[sp2] = pml[((size_t)row * SPLIT + sp2) * 2 + 1];
        M = fmaxf(M, mv[sp2]);
    }
    float L = 0.f;
    f32x4 acc = {};
#pragma unroll
    for (int sp2 = 0; sp2 < SPLIT; ++sp2) {
        float w = __expf(mv[sp2] - M);
        L += lv[sp2] * w;
        f32x4 v = *(const f32x4*)&po[((size_t)row * SPLIT + sp2) * D_DIM + dg * 4];
#pragma unroll
        for (int j = 0; j < 4; ++j) acc[j] += w * v[j];
    }
    float inv = 1.0f / L;
    bf16x4 o4;
#pragma unroll
    for (int j = 0; j < 4; ++j) o4[j] = (__bf16)(acc[j] * inv);
    *(bf16x4*)&attn[((size_t)(t * B_DIM + b)) * E_DIM + h * D_DIM + dg * 4] = o4;
}

// ---------------- Kernel 3: output projection ----------------
__global__ __launch_bounds__(256)
void oproj_kernel(const __bf16* __restrict__ X, const __bf16* __restrict__ Wo,
                  const float* __restrict__ bo, float* __restrict__ out) {
    __shared__ __align__(16) __bf16 Xs[64][136];
    __shared__ __align__(16) __bf16 Ws[64][136];
    const int m0 = blockIdx.x * 64;
    const int n0 = blockIdx.y * 64;
    const int tid = threadIdx.x;
    const int wid = tid >> 6, lane = tid & 63;
    const int wm = (wid & 1) * 32, wn = (wid >> 1) * 32;
    const int lr = lane & 15, lg = lane >> 4;

    f32x4 acc[2][2] = {};
    for (int kc = 0; kc < 2; ++kc) {
        for (int c = tid; c < 1024; c += 256) {
            int row = c >> 4, col = (c & 15) * 8;
            *(bf16x8*)&Xs[row][col] = *(const bf16x8*)&X[(size_t)(m0 + row) * E_DIM + kc * 128 + col];
            *(bf16x8*)&Ws[row][col] = *(const bf16x8*)&Wo[(size_t)(n0 + row) * E_DIM + kc * 128 + col];
        }
        __syncthreads();
#pragma unroll
        for (int ks = 0; ks < 4; ++ks) {
            bf16x8 a0 = *(const bf16x8*)&Xs[wm + lr][ks * 32 + lg * 8];
            bf16x8 a1 = *(const bf16x8*)&Xs[wm + 16 + lr][ks * 32 + lg * 8];
            bf16x8 b0 = *(const bf16x8*)&Ws[wn + lr][ks * 32 + lg * 8];
            bf16x8 b1 = *(const bf16x8*)&Ws[wn + 16 + lr][ks * 32 + lg * 8];
            acc[0][0] = __builtin_amdgcn_mfma_f32_16x16x32_bf16(a0, b0, acc[0][0], 0, 0, 0);
            acc[0][1] = __builtin_amdgcn_mfma_f32_16x16x32_bf16(a0, b1, acc[0][1], 0, 0, 0);
            acc[1][0] = __builtin_amdgcn_mfma_f32_16x16x32_bf16(a1, b0, acc[1][0], 0, 0, 0);
            acc[1][1] = __builtin_amdgcn_mfma_f32_16x16x32_bf16(a1, b1, acc[1][1], 0, 0, 0);
        }
        __syncthreads();
    }
#pragma unroll
    for (int mt = 0; mt < 2; ++mt) {
#pragma unroll
        for (int nt = 0; nt < 2; ++nt) {
            int n = n0 + wn + nt * 16 + lr;
            float bb = bo[n];
#pragma unroll
            for (int r = 0; r < 4; ++r) {
                int m = m0 + wm + mt * 16 + lg * 4 + r;
                out[(size_t)m * E_DIM + n] = acc[mt][nt][r] + bb;
            }
        }
    }
}

extern "C" void kernel_launch(void* const* d_in, const int* in_sizes, int n_in,
                              void* d_out, int out_size, void* d_ws, size_t ws_size,
                              hipStream_t stream) {
    const float* query     = (const float*)d_in[0];
    const float* attn_bias = (const float*)d_in[1];
    const float* Wq = (const float*)d_in[2];
    const float* bq = (const float*)d_in[3];
    const float* Wk = (const float*)d_in[4];
    const float* bk = (const float*)d_in[5];
    const float* Wv = (const float*)d_in[6];
    const float* bv = (const float*)d_in[7];
    const float* Wo = (const float*)d_in[8];
    const float* bo = (const float*)d_in[9];
    float* out = (float*)d_out;

    char* ws = (char*)d_ws;
    __bf16* Xbf  = (__bf16*)(ws);                         // 2 MB
    __bf16* Wall = (__bf16*)(ws + 2097152);               // 4 x 128 KB contiguous (q,k,v,o)
    __bf16* qhp  = (__bf16*)(ws + 2621440);               // [B][H][T][D] 2 MB
    __bf16* khp  = (__bf16*)(ws + 4718592);               // [B][H][T][D] 2 MB
    __bf16* vTp  = (__bf16*)(ws + 6815744);               // [B][H][D][T] 2 MB
    __bf16* attn = (__bf16*)(ws + 8912896);               // [M][E] 2 MB
    float*  po   = (float*)(ws + 11010048);               // [BH*T][SPLIT][32] f32 = 16 MB
    float*  pml  = (float*)(ws + 27787264);               // [BH*T][SPLIT][2]  f32 = 1 MB

    // single fused convert: query + all 4 weights
    cvt_all_kernel<<<dim3((M_DIM * E_DIM + 4 * E_DIM * E_DIM) / 1024), 256, 0, stream>>>(
        query, Wq, Wk, Wv, Wo, Xbf, Wall);

    // QKV projection
    qkv_kernel<<<dim3(M_DIM / 64, 12), 256, 0, stream>>>(Xbf, Wall, bq, bk, bv, qhp, khp, vTp);

    // attention (split over S) + combine
    attn_kernel<<<dim3(T_DIM / 64, B_DIM * H_DIM, SPLIT), 256, 0, stream>>>(
        qhp, khp, vTp, attn_bias, po, pml);
    combine_kernel<<<dim3(B_DIM * H_DIM * T_DIM * 8 / 256), 256, 0, stream>>>(po, pml, attn);

    // output projection
    oproj_kernel<<<dim3(M_DIM / 64, E_DIM / 64), 256, 0, stream>>>(
        attn, Wall + 3 * E_DIM * E_DIM, bo, out);
}